// Round 6
// baseline (1407.408 us; speedup 1.0000x reference)
//
#include <hip/hip_runtime.h>
#include <hip/hip_bf16.h>
#include <stdint.h>

typedef float  f32x4  __attribute__((ext_vector_type(4)));
typedef __bf16 bf16x8 __attribute__((ext_vector_type(8)));
typedef unsigned short u16x8 __attribute__((ext_vector_type(8)));

__device__ __forceinline__ unsigned short f2bf_rne(float f) {
    uint32_t x = __float_as_uint(f);
    uint32_t r = x + 0x7FFFu + ((x >> 16) & 1u);
    return (unsigned short)(r >> 16);
}

__global__ __launch_bounds__(256) void cvt_f32_bf16(const float* __restrict__ src,
                                                    unsigned short* __restrict__ dst,
                                                    long n) {
    long i0 = ((long)blockIdx.x * blockDim.x + threadIdx.x) * 8;
    long stride = (long)gridDim.x * blockDim.x * 8;
    for (long j = i0; j + 8 <= n; j += stride) {
        float4 v0 = *(const float4*)(src + j);
        float4 v1 = *(const float4*)(src + j + 4);
        u16x8 o;
        o[0] = f2bf_rne(v0.x); o[1] = f2bf_rne(v0.y);
        o[2] = f2bf_rne(v0.z); o[3] = f2bf_rne(v0.w);
        o[4] = f2bf_rne(v1.x); o[5] = f2bf_rne(v1.y);
        o[6] = f2bf_rne(v1.z); o[7] = f2bf_rne(v1.w);
        *(u16x8*)(dst + j) = o;
    }
}

#define GLL(SRC, DST) __builtin_amdgcn_global_load_lds(                      \
    (const __attribute__((address_space(1))) void*)(SRC),                    \
    (__attribute__((address_space(3))) void*)(DST), 16, 0, 0)
#define BARRIER() asm volatile("s_barrier" ::: "memory")
#define WAITV(N) asm volatile("s_waitcnt vmcnt(" #N ")" ::: "memory")

// 256x256 tile, BK=64, 8 waves (2M x 4N), 128 KiB double-buffered LDS,
// 16x16x32 MFMA with the round-2-verified ZERO-conflict LDS layout.
// FREE-RUN tile body: 2 barriers per K-tile. vmcnt LEDGER (per wave):
// each tile = 8 GLLs. Prologue: issue 16 (tiles 0,1), WAITV(8) drains tile0.
// Loop iter t: stage t+2 (+8 -> 16 outstanding), WAITV(8) drains tile t+1,
// BARRIER makes it visible. Tile t+2's 8 stay in flight across the next
// whole tile (~2400 cyc > 900 cyc HBM latency).
__global__ __launch_bounds__(512, 2) void gemm256_fr(
    const unsigned short* __restrict__ A, const unsigned short* __restrict__ B,
    const float* __restrict__ bias, float* __restrict__ C,
    int M, int N, int K) {
    __shared__ __align__(16) char lds[131072];
    const int tid  = threadIdx.x;
    const int lane = tid & 63;
    const int wave = tid >> 6;
    const int wr  = wave >> 2;   // 0..1
    const int wc  = wave & 3;    // 0..3
    const int l15 = lane & 15;
    const int l4  = lane >> 4;

    // bijective XCD swizzle
    int bid = blockIdx.x, nwg = gridDim.x;
    int qq = nwg >> 3, rr = nwg & 7, xc = bid & 7, oo = bid >> 3;
    int wg = (xc < rr ? xc * (qq + 1) : rr * (qq + 1) + (xc - rr) * qq) + oo;
    const int nTn = N >> 8;
    const long m0 = (long)(wg / nTn) << 8;
    const long n0 = (long)(wg % nTn) << 8;

    const int colSw = ((tid & 7) ^ ((tid >> 3) & 7)) << 3;
    const int aRow  = tid >> 3;
    const int bWcLo = tid >> 8;
    const int bR    = (tid >> 3) & 31;
    const long Kl = K;

    // staging layout identical to round 2 (verified conflict-free + correct)
    auto STAGE_A = [&](int buf, int u, int t) {
        char* dst = lds + (buf << 16) + (u << 14) + tid * 16;
        long col = (long)t * 64 + colSw;
#pragma unroll
        for (int i = 0; i < 2; ++i) {
            const unsigned short* src = A + (m0 + i * 128 + u * 64 + aRow) * Kl + col;
            GLL(src, dst + i * 8192);
        }
    };
    auto STAGE_B = [&](int buf, int u, int t) {
        char* dst = lds + (buf << 16) + 32768 + (u << 14) + tid * 16;
        long col = (long)t * 64 + colSw;
#pragma unroll
        for (int i = 0; i < 2; ++i) {
            const unsigned short* src = B + (n0 + (i * 2 + bWcLo) * 64 + u * 32 + bR) * Kl + col;
            GLL(src, dst + i * 8192);
        }
    };
    auto LDA = [&](int buf, int mh, int m, int kk) -> bf16x8 {
        int off = (((m * 16 + l15) * 64 + kk * 32 + l4 * 8) * 2) ^ ((l15 & 7) << 4);
        return *(const bf16x8*)(lds + (buf << 16) + (mh << 14) + (wr << 13) + off);
    };
    auto LDB = [&](int buf, int nh, int n, int kk) -> bf16x8 {
        int off = (((n * 16 + l15) * 64 + kk * 32 + l4 * 8) * 2) ^ ((l15 & 7) << 4);
        return *(const bf16x8*)(lds + (buf << 16) + 32768 + (nh << 14) + (wc << 12) + off);
    };

    f32x4 acc[8][4] = {};               // 128 regs
    bf16x8 af[4][2], af2[4][2];         // 64 regs
    bf16x8 bq[2][2], bq2[2][2];         // 32 regs

    auto MFMA_Q = [&](bf16x8 (&a_)[4][2], bf16x8 (&b_)[2][2], int mo, int no) {
        __builtin_amdgcn_s_setprio(1);
#pragma unroll
        for (int kk = 0; kk < 2; ++kk)
#pragma unroll
            for (int m = 0; m < 4; ++m)
#pragma unroll
                for (int n = 0; n < 2; ++n)
                    acc[mo + m][no + n] = __builtin_amdgcn_mfma_f32_16x16x32_bf16(
                        a_[m][kk], b_[n][kk], acc[mo + m][no + n], 0, 0, 0);
        __builtin_amdgcn_s_setprio(0);
    };

    const int NT = K >> 6;

    // prologue: stage tiles 0 and 1 (8 GLL each); drain tile 0, keep tile 1 in flight
    STAGE_A(0, 0, 0); STAGE_A(0, 1, 0); STAGE_B(0, 0, 0); STAGE_B(0, 1, 0);
    STAGE_A(1, 0, 1); STAGE_A(1, 1, 1); STAGE_B(1, 0, 1); STAGE_B(1, 1, 1);
    WAITV(8);
    BARRIER();

    for (int t = 0; t < NT; ++t) {
        const int c = t & 1;
        // ---- free-run compute on buf c: 20 ds_reads + 64 MFMA, no explicit waits ----
#pragma unroll
        for (int m = 0; m < 4; ++m) { af[m][0] = LDA(c, 0, m, 0); af[m][1] = LDA(c, 0, m, 1); }
#pragma unroll
        for (int n = 0; n < 2; ++n) { bq[n][0] = LDB(c, 0, n, 0); bq[n][1] = LDB(c, 0, n, 1); }
        MFMA_Q(af, bq, 0, 0);                       // Q00
#pragma unroll
        for (int n = 0; n < 2; ++n) { bq2[n][0] = LDB(c, 1, n, 0); bq2[n][1] = LDB(c, 1, n, 1); }
        MFMA_Q(af, bq2, 0, 2);                      // Q01
#pragma unroll
        for (int m = 0; m < 4; ++m) { af2[m][0] = LDA(c, 1, m, 0); af2[m][1] = LDA(c, 1, m, 1); }
        MFMA_Q(af2, bq2, 4, 2);                     // Q11
        MFMA_Q(af2, bq, 4, 0);                      // Q10 (reuses bq — no re-read)

        // ---- fence: all waves done reading buf c -> safe to re-stage it ----
        BARRIER();
        if (t + 2 < NT) {
            STAGE_A(c, 0, t + 2); STAGE_A(c, 1, t + 2);
            STAGE_B(c, 0, t + 2); STAGE_B(c, 1, t + 2);
            WAITV(8);             // 16 outstanding -> drain tile t+1's 8, keep t+2's 8
            BARRIER();            // tile t+1 now visible to all waves
        } else if (t + 1 < NT) {
            WAITV(0);             // drain tile t+1 (last one)
            BARRIER();
        }
    }

    // epilogue: D mapping col = l15, row = l4*4 + j within each 16x16 fragment
#pragma unroll
    for (int nf = 0; nf < 4; ++nf) {
        const long col = n0 + wc * 64 + nf * 16 + l15;
        const float bv = bias[col];
#pragma unroll
        for (int mf = 0; mf < 8; ++mf) {
            float* Cp = C + (m0 + wr * 128 + mf * 16 + l4 * 4) * (long)N + col;
#pragma unroll
            for (int j = 0; j < 4; ++j)
                Cp[(long)j * N] = acc[mf][nf][j] + bv;
        }
    }
}

// fallback: m97-structure 128x128 (verified round 1) for non-conforming shapes
__global__ __launch_bounds__(256) void gemm_bt_bias(const unsigned short* __restrict__ A,
                                                    const unsigned short* __restrict__ B,
                                                    const float* __restrict__ bias,
                                                    float* __restrict__ C,
                                                    int M, int N, int K) {
    __shared__ unsigned short lds_a[128 * 32];
    __shared__ unsigned short lds_b[128 * 32];
    const int tid  = threadIdx.x;
    const int lane = tid & 63;
    const int wave = tid >> 6;
    const int wrr = wave >> 1, wcc = wave & 1;
    const int l15 = lane & 15, l4 = lane >> 4;
    const int nTilesN = N / 128;
    const long m0 = (long)(blockIdx.x / nTilesN) * 128;
    const long n0 = (long)(blockIdx.x % nTilesN) * 128;
    f32x4 acc[4][4] = {};
    const unsigned short* aSrc = A + (m0 + (tid >> 2)) * (long)K + ((tid & 3) * 8);
    const unsigned short* bSrc = B + (n0 + (tid >> 2)) * (long)K + ((tid & 3) * 8);
    char* aDst = (char*)lds_a + tid * 16;
    char* bDst = (char*)lds_b + tid * 16;
    for (int k0 = 0; k0 < K; k0 += 32) {
#pragma unroll
        for (int i = 0; i < 2; i++) {
            GLL(aSrc + (long)i * 64 * K + k0, aDst + i * 4096);
            GLL(bSrc + (long)i * 64 * K + k0, bDst + i * 4096);
        }
        __syncthreads();
        bf16x8 afr[4], bfr[4];
#pragma unroll
        for (int r = 0; r < 4; r++)
            afr[r] = *(const bf16x8*)&lds_a[(wrr * 64 + r * 16 + l15) * 32 + l4 * 8];
#pragma unroll
        for (int c = 0; c < 4; c++)
            bfr[c] = *(const bf16x8*)&lds_b[(wcc * 64 + c * 16 + l15) * 32 + l4 * 8];
#pragma unroll
        for (int r = 0; r < 4; r++)
#pragma unroll
            for (int c = 0; c < 4; c++)
                acc[r][c] = __builtin_amdgcn_mfma_f32_16x16x32_bf16(afr[r], bfr[c], acc[r][c], 0, 0, 0);
        __syncthreads();
    }
#pragma unroll
    for (int c = 0; c < 4; c++) {
        const long n = n0 + wcc * 64 + c * 16 + l15;
        const float bv = bias[n];
#pragma unroll
        for (int r = 0; r < 4; r++) {
            const long m = m0 + wrr * 64 + r * 16 + l4 * 4;
            float* Cp = C + m * (long)N + n;
#pragma unroll
            for (int j = 0; j < 4; j++)
                Cp[(long)j * N] = acc[r][c][j] + bv;
        }
    }
}

extern "C" void kernel_launch(void* const* d_in, const int* in_sizes, int n_in,
                              void* d_out, int out_size, void* d_ws, size_t ws_size,
                              hipStream_t stream) {
    const float* x    = (const float*)d_in[0];
    const float* w    = (const float*)d_in[1];
    const float* bias = (const float*)d_in[2];
    float* out = (float*)d_out;

    const long Nn = in_sizes[2];             // OUT = 4096
    const long Kk = (long)in_sizes[1] / Nn;  // IN  = 16384
    const long Mm = (long)in_sizes[0] / Kk;  // B*S = 8192

    unsigned short* aB = (unsigned short*)d_ws;
    unsigned short* bB = aB + Mm * Kk;
    cvt_f32_bf16<<<2048, 256, 0, stream>>>(x, aB, Mm * Kk);
    cvt_f32_bf16<<<2048, 256, 0, stream>>>(w, bB, Nn * Kk);

    if ((Mm & 255) == 0 && (Nn & 255) == 0 && (Kk & 63) == 0 && Kk >= 256) {
        const int grid = (int)((Mm >> 8) * (Nn >> 8));
        gemm256_fr<<<grid, 512, 0, stream>>>(aB, bB, bias, out, (int)Mm, (int)Nn, (int)Kk);
    } else {
        const int grid = (int)((Mm / 128) * (Nn / 128));
        gemm_bt_bias<<<grid, 256, 0, stream>>>(aB, bB, bias, out, (int)Mm, (int)Nn, (int)Kk);
    }
}